// Round 23
// baseline (439.451 us; speedup 1.0000x reference)
//
#include <hip/hip_runtime.h>
#include <hip/hip_bf16.h>

#define N_NODES 40000
#define M_PAD   40064            // 313 * 128
#define N_EDGES 640000
#define DIM_H 512
#define QKV_STRIDE 1536          // row stride in u16 units (3072 B)
#define ROW_BYTES 3072
// Row layout (bytes): [0,1024) Q bf16 | [1024,1536) K int8 | [2048,2560) V int8
// Per-(row,head) scales in dense side arrays ksc/vsc (L2-resident) — r20:
// moved OUT of the row (r19's inline scales cost +1 cache line per gather).

typedef __attribute__((ext_vector_type(8))) short bf16x8_t;  // 8 bf16 = 4 VGPR
typedef __attribute__((ext_vector_type(4))) float f32x4_t;   // MFMA acc
typedef __attribute__((ext_vector_type(8))) unsigned short u16x8_t;

static __device__ __forceinline__ unsigned short f2bf(float f) {
    __hip_bfloat16 h = __float2bfloat16(f);
    return *reinterpret_cast<unsigned short*>(&h);
}
static __device__ __forceinline__ float bf2f(unsigned short u) {
    return __uint_as_float(((unsigned)u) << 16);
}
// async global->LDS, 16B per lane (linear LDS dest = uniform base + lane*16).
static __device__ __forceinline__ void gll16(const void* g, void* l) {
    __builtin_amdgcn_global_load_lds(
        (const __attribute__((address_space(1))) unsigned int*)g,
        (__attribute__((address_space(3))) unsigned int*)l, 16, 0, 0);
}

// ---------------------------------------------------------------------------
// K0a: cast x (f32) -> xb (bf16). 8 elems/thread. 10000 blocks exact.
// ---------------------------------------------------------------------------
__global__ __launch_bounds__(256)
void cast_x(const float* __restrict__ x, unsigned short* __restrict__ xb)
{
    const size_t i = ((size_t)blockIdx.x * 256 + threadIdx.x) * 8;
    const float4 v0 = *(const float4*)&x[i];
    const float4 v1 = *(const float4*)&x[i + 4];
    u16x8_t o;
    o[0] = f2bf(v0.x); o[1] = f2bf(v0.y); o[2] = f2bf(v0.z); o[3] = f2bf(v0.w);
    o[4] = f2bf(v1.x); o[5] = f2bf(v1.y); o[6] = f2bf(v1.z); o[7] = f2bf(v1.w);
    *(u16x8_t*)&xb[i] = o;
}

// ---------------------------------------------------------------------------
// K0b: cast+transpose W[k][n] -> Wt[m][n][k] (bf16). grid (16,16,3).
// ---------------------------------------------------------------------------
__global__ __launch_bounds__(256)
void cast_wt(const float* __restrict__ Wq,
             const float* __restrict__ Wk,
             const float* __restrict__ Wv,
             unsigned short* __restrict__ Wt)
{
    __shared__ float tile[32][33];
    const float* W = (blockIdx.z == 0) ? Wq : (blockIdx.z == 1) ? Wk : Wv;
    unsigned short* Wo = Wt + (size_t)blockIdx.z * 512 * 512;
    const int k0 = blockIdx.x * 32, n0 = blockIdx.y * 32;
    const int tx = threadIdx.x & 31, ty0 = threadIdx.x >> 5;
    #pragma unroll
    for (int p = 0; p < 4; ++p) {
        const int r = ty0 + p * 8;
        tile[r][tx] = W[(size_t)(k0 + r) * 512 + n0 + tx];
    }
    __syncthreads();
    #pragma unroll
    for (int p = 0; p < 4; ++p) {
        const int r = ty0 + p * 8;
        Wo[(size_t)(n0 + r) * 512 + k0 + tx] = f2bf(tile[tx][r]);
    }
}

// ---------------------------------------------------------------------------
// K1: QKV GEMM (r13 core: 128x128 tile, BK=32, chunk-swizzled staging,
// XCD-bijective remap). r19 fused-epilogue quant; r20: scales -> dense
// side arrays ksc/vsc[node*8+hd] (not inline: avoids +1 line/gather).
// ---------------------------------------------------------------------------
__global__ __launch_bounds__(256)
void qkv_gemm_mfma(const unsigned short* __restrict__ xb,
                   const unsigned short* __restrict__ Wt,
                   unsigned short* __restrict__ qkv,
                   float* __restrict__ ksc,
                   float* __restrict__ vsc)
{
    __shared__ short Asub[128 * 32];
    __shared__ short Bsub[128 * 32];

    const int orig = blockIdx.x;             // 0..3755
    const int q = 469, rmod = 4;             // 3756 = 8*469 + 4
    const int xcd = orig & 7;
    const int sub = orig >> 3;
    const int wg = (xcd < rmod ? xcd * (q + 1) : rmod * (q + 1) + (xcd - rmod) * q) + sub;
    const int n0g = (wg % 12) * 128;
    const int m0  = (wg / 12) * 128;

    const int wsel = n0g >> 9;
    const int nc0  = n0g & 511;
    const int tid = threadIdx.x;
    const int l = tid & 63;
    const int w = tid >> 6;
    const int wr = w >> 1, wc = w & 1;
    const int lr = l & 15;
    const int lk = (l >> 4) * 8;             // chunk index = lk>>3 in {0..3}

    const int idx0 = tid, idx1 = 256 + tid;
    const int ar0 = idx0 >> 2, ac0 = (((idx0 & 3) ^ ((idx0 >> 3) & 3))) * 8;
    const int ar1 = idx1 >> 2, ac1 = (((idx1 & 3) ^ ((idx1 >> 3) & 3))) * 8;

    const unsigned short* Abase = xb + (size_t)m0 * 512;
    const unsigned short* Bbase = Wt + (size_t)wsel * 262144 + (size_t)nc0 * 512;

    f32x4_t acc[4][4];
    #pragma unroll
    for (int i = 0; i < 4; ++i)
        #pragma unroll
        for (int j = 0; j < 4; ++j)
            acc[i][j] = {0.f, 0.f, 0.f, 0.f};

    for (int k0 = 0; k0 < 512; k0 += 32) {
        gll16(Abase + (size_t)ar0 * 512 + k0 + ac0, &Asub[idx0 * 8]);
        gll16(Abase + (size_t)ar1 * 512 + k0 + ac1, &Asub[idx1 * 8]);
        gll16(Bbase + (size_t)ar0 * 512 + k0 + ac0, &Bsub[idx0 * 8]);
        gll16(Bbase + (size_t)ar1 * 512 + k0 + ac1, &Bsub[idx1 * 8]);
        __syncthreads();
        bf16x8_t a[4], b[4];
        #pragma unroll
        for (int fm = 0; fm < 4; ++fm) {
            const int Ra = wr * 64 + fm * 16 + lr;
            const int pa = (((lk >> 3) ^ ((Ra >> 1) & 3))) << 3;
            a[fm] = *(const bf16x8_t*)&Asub[Ra * 32 + pa];
        }
        #pragma unroll
        for (int fn = 0; fn < 4; ++fn) {
            const int Rb = wc * 64 + fn * 16 + lr;
            const int pb = (((lk >> 3) ^ ((Rb >> 1) & 3))) << 3;
            b[fn] = *(const bf16x8_t*)&Bsub[Rb * 32 + pb];
        }
        #pragma unroll
        for (int fm = 0; fm < 4; ++fm)
            #pragma unroll
            for (int fn = 0; fn < 4; ++fn)
                acc[fm][fn] = __builtin_amdgcn_mfma_f32_16x16x32_bf16(
                                  a[fm], b[fn], acc[fm][fn], 0, 0, 0);
        __syncthreads();
    }

    if (wsel == 0) {
        // Q section: bf16 write (unchanged)
        #pragma unroll
        for (int fm = 0; fm < 4; ++fm)
            #pragma unroll
            for (int fn = 0; fn < 4; ++fn)
                #pragma unroll
                for (int j = 0; j < 4; ++j) {
                    const int row = m0 + wr * 64 + fm * 16 + (l >> 4) * 4 + j;
                    const int col = n0g + wc * 64 + fn * 16 + lr;
                    qkv[(size_t)row * QKV_STRIDE + col] = f2bf(acc[fm][fn][j]);
                }
    } else {
        // K (wsel==1) / V (wsel==2): int8 + per-(row,head) scale to side array.
        const int hd    = (nc0 >> 6) + wc;               // head 0..7
        const int sbase = (wsel == 1) ? 1024 : 2048;     // int8 data base
        float* sc       = (wsel == 1) ? ksc : vsc;
        #pragma unroll
        for (int fm = 0; fm < 4; ++fm)
            #pragma unroll
            for (int j = 0; j < 4; ++j) {
                const int row = m0 + wr * 64 + fm * 16 + (l >> 4) * 4 + j;
                float m = 0.f;
                #pragma unroll
                for (int fn = 0; fn < 4; ++fn)
                    m = fmaxf(m, fabsf(acc[fm][fn][j]));
                m = fmaxf(m, __shfl_xor(m, 1, 64));
                m = fmaxf(m, __shfl_xor(m, 2, 64));
                m = fmaxf(m, __shfl_xor(m, 4, 64));
                m = fmaxf(m, __shfl_xor(m, 8, 64));
                const float inv = (m > 0.f) ? 127.0f / m : 0.f;
                char* rowb = (char*)qkv + (size_t)row * ROW_BYTES;
                #pragma unroll
                for (int fn = 0; fn < 4; ++fn) {
                    const int qv = (int)rintf(acc[fm][fn][j] * inv);
                    rowb[sbase + hd * 64 + fn * 16 + lr] = (char)(signed char)qv;
                }
                if (lr == 0)
                    sc[(size_t)row * 8 + hd] = m * (1.0f / 127.0f);
            }
    }
}

// ---------------------------------------------------------------------------
// CSR build (by dst).
// ---------------------------------------------------------------------------
__global__ __launch_bounds__(256)
void csr_hist(const int* __restrict__ ei, int* __restrict__ counts)
{
    const int e = blockIdx.x * 256 + threadIdx.x;   // 2500 blocks exact
    atomicAdd(&counts[ei[N_EDGES + e]], 1);
}

__global__ __launch_bounds__(1024)
void csr_scan(const int* __restrict__ counts, int* __restrict__ row_ptr)
{
    __shared__ int part[1024];
    const int t = threadIdx.x;
    const int base = t * 40;
    int s = 0;
    for (int i = 0; i < 40; ++i) {
        const int idx = base + i;
        if (idx < N_NODES) s += counts[idx];
    }
    part[t] = s;
    __syncthreads();
    for (int off = 1; off < 1024; off <<= 1) {
        int v = (t >= off) ? part[t - off] : 0;
        __syncthreads();
        part[t] += v;
        __syncthreads();
    }
    int run = (t == 0) ? 0 : part[t - 1];
    for (int i = 0; i < 40; ++i) {
        const int idx = base + i;
        if (idx < N_NODES) { row_ptr[idx] = run; run += counts[idx]; }
    }
    if (t == 0) row_ptr[N_NODES] = part[1023];
}

__global__ __launch_bounds__(256)
void csr_scatter(const int* __restrict__ ei, const int* __restrict__ row_ptr,
                 int* __restrict__ cursor, unsigned short* __restrict__ col)
{
    const int e = blockIdx.x * 256 + threadIdx.x;   // 2500 blocks exact
    const int dst = ei[N_EDGES + e];
    const int pos = atomicAdd(&cursor[dst], 1);
    col[row_ptr[dst] + pos] = (unsigned short)ei[e];
}

// ---------------------------------------------------------------------------
// K2: FUSED edge pass (r16/r18 config: 2-wave blocks, grid 20000).
// r20: per-head scales from dense L2-resident arrays (ksc/vsc[s*8+g]).
// ---------------------------------------------------------------------------
__global__ __launch_bounds__(128)
void edge_fused(const unsigned short* __restrict__ qkv,
                const float* __restrict__ ksc,
                const float* __restrict__ vsc,
                const int* __restrict__ row_ptr,
                const unsigned short* __restrict__ col,
                const float* __restrict__ x,
                float* __restrict__ out)
{
    const int node = blockIdx.x * 2 + (threadIdx.x >> 6);
    const int lane = threadIdx.x & 63;
    const int g = lane >> 3;
    const int d0b = lane * 8;

    const u16x8_t q8 = *(const u16x8_t*)(qkv + (size_t)node * QKV_STRIDE + lane * 8);
    float q[8];
    #pragma unroll
    for (int j = 0; j < 8; ++j) q[j] = bf2f(q8[j]);

    const char* qb = (const char*)qkv;
    float acc[8] = {0.f, 0.f, 0.f, 0.f, 0.f, 0.f, 0.f, 0.f};
    float zsum = 0.f;
    const int start = row_ptr[node];
    const int end   = row_ptr[node + 1];

    int e = start;
    for (; e + 4 <= end; e += 4) {
        const int s0 = col[e], s1 = col[e + 1], s2 = col[e + 2], s3 = col[e + 3];
        const char* rb0 = qb + (size_t)s0 * ROW_BYTES;
        const char* rb1 = qb + (size_t)s1 * ROW_BYTES;
        const char* rb2 = qb + (size_t)s2 * ROW_BYTES;
        const char* rb3 = qb + (size_t)s3 * ROW_BYTES;
        const uint2 k0 = *(const uint2*)(rb0 + 1024 + d0b);
        const uint2 k1 = *(const uint2*)(rb1 + 1024 + d0b);
        const uint2 k2 = *(const uint2*)(rb2 + 1024 + d0b);
        const uint2 k3 = *(const uint2*)(rb3 + 1024 + d0b);
        const uint2 v0 = *(const uint2*)(rb0 + 2048 + d0b);
        const uint2 v1 = *(const uint2*)(rb1 + 2048 + d0b);
        const uint2 v2 = *(const uint2*)(rb2 + 2048 + d0b);
        const uint2 v3 = *(const uint2*)(rb3 + 2048 + d0b);
        const float ks0 = ksc[(size_t)s0 * 8 + g];
        const float ks1 = ksc[(size_t)s1 * 8 + g];
        const float ks2 = ksc[(size_t)s2 * 8 + g];
        const float ks3 = ksc[(size_t)s3 * 8 + g];
        const signed char* ck0 = (const signed char*)&k0;
        const signed char* ck1 = (const signed char*)&k1;
        const signed char* ck2 = (const signed char*)&k2;
        const signed char* ck3 = (const signed char*)&k3;
        float p0 = 0.f, p1 = 0.f, p2 = 0.f, p3 = 0.f;
        #pragma unroll
        for (int j = 0; j < 8; ++j) {
            p0 = fmaf((float)ck0[j], q[j], p0);
            p1 = fmaf((float)ck1[j], q[j], p1);
            p2 = fmaf((float)ck2[j], q[j], p2);
            p3 = fmaf((float)ck3[j], q[j], p3);
        }
        p0 += __shfl_xor(p0, 1, 64); p0 += __shfl_xor(p0, 2, 64); p0 += __shfl_xor(p0, 4, 64);
        p1 += __shfl_xor(p1, 1, 64); p1 += __shfl_xor(p1, 2, 64); p1 += __shfl_xor(p1, 4, 64);
        p2 += __shfl_xor(p2, 1, 64); p2 += __shfl_xor(p2, 2, 64); p2 += __shfl_xor(p2, 4, 64);
        p3 += __shfl_xor(p3, 1, 64); p3 += __shfl_xor(p3, 2, 64); p3 += __shfl_xor(p3, 4, 64);
        const float sc0 = __expf(fminf(fmaxf(p0 * ks0 * 0.125f, -5.f), 5.f));
        const float sc1 = __expf(fminf(fmaxf(p1 * ks1 * 0.125f, -5.f), 5.f));
        const float sc2 = __expf(fminf(fmaxf(p2 * ks2 * 0.125f, -5.f), 5.f));
        const float sc3 = __expf(fminf(fmaxf(p3 * ks3 * 0.125f, -5.f), 5.f));
        zsum += (sc0 + sc1) + (sc2 + sc3);
        const float scv0 = sc0 * vsc[(size_t)s0 * 8 + g];
        const float scv1 = sc1 * vsc[(size_t)s1 * 8 + g];
        const float scv2 = sc2 * vsc[(size_t)s2 * 8 + g];
        const float scv3 = sc3 * vsc[(size_t)s3 * 8 + g];
        const signed char* cv0 = (const signed char*)&v0;
        const signed char* cv1 = (const signed char*)&v1;
        const signed char* cv2 = (const signed char*)&v2;
        const signed char* cv3 = (const signed char*)&v3;
        #pragma unroll
        for (int j = 0; j < 8; ++j) {
            float a = acc[j];
            a = fmaf(scv0, (float)cv0[j], a);
            a = fmaf(scv1, (float)cv1[j], a);
            a = fmaf(scv2, (float)cv2[j], a);
            a = fmaf(scv3, (float)cv3[j], a);
            acc[j] = a;
        }
    }
    for (; e < end; ++e) {
        const int s0 = col[e];
        const char* rb0 = qb + (size_t)s0 * ROW_BYTES;
        const uint2 k0 = *(const uint2*)(rb0 + 1024 + d0b);
        const uint2 v0 = *(const uint2*)(rb0 + 2048 + d0b);
        const float ks0 = ksc[(size_t)s0 * 8 + g];
        const signed char* ck0 = (const signed char*)&k0;
        float p0 = 0.f;
        #pragma unroll
        for (int j = 0; j < 8; ++j) p0 = fmaf((float)ck0[j], q[j], p0);
        p0 += __shfl_xor(p0, 1, 64); p0 += __shfl_xor(p0, 2, 64); p0 += __shfl_xor(p0, 4, 64);
        const float sc0 = __expf(fminf(fmaxf(p0 * ks0 * 0.125f, -5.f), 5.f));
        zsum += sc0;
        const float scv0 = sc0 * vsc[(size_t)s0 * 8 + g];
        const signed char* cv0 = (const signed char*)&v0;
        #pragma unroll
        for (int j = 0; j < 8; ++j) acc[j] = fmaf(scv0, (float)cv0[j], acc[j]);
    }

    const float invz = 1.0f / (zsum + 1e-6f);
    const float* xr = x + (size_t)node * 512 + lane * 8;
    float xv[8];
    #pragma unroll
    for (int j = 0; j < 8; ++j) xv[j] = __builtin_nontemporal_load(xr + j);
    float* orow = out + (size_t)node * 512 + lane * 8;
    #pragma unroll
    for (int j = 0; j < 8; ++j)
        __builtin_nontemporal_store(xv[j] + acc[j] * invz, orow + j);
}

// ---------------------------------------------------------------------------
// K3: BN column stats over final h (in d_out). thread=col, 80 rows/block.
// ---------------------------------------------------------------------------
__global__ __launch_bounds__(512)
void stats_pass(const float* __restrict__ hbuf, float* __restrict__ stats)
{
    const int c  = threadIdx.x;
    const int r0 = blockIdx.x * 80;
    float sum = 0.f, sq = 0.f;
    for (int i = 0; i < 80; ++i) {
        const float hv = hbuf[(size_t)(r0 + i) * 512 + c];
        sum += hv; sq += hv * hv;
    }
    atomicAdd(&stats[c], sum);
    atomicAdd(&stats[512 + c], sq);
}

// ---------------------------------------------------------------------------
// K4: BatchNorm normalize in place. float4/thread, 20000 blocks exact.
// ---------------------------------------------------------------------------
__global__ __launch_bounds__(256)
void bn_norm(float* __restrict__ hbuf,
             const float* __restrict__ stats,
             const float* __restrict__ gamma,
             const float* __restrict__ beta)
{
    const size_t i4 = ((size_t)blockIdx.x * 256 + threadIdx.x) * 4;
    const int c = (int)(i4 & 511);
    const float invN = 1.0f / 40000.0f;
    float4 h = *(float4*)&hbuf[i4];
    float hv[4] = {h.x, h.y, h.z, h.w};
    float o[4];
    #pragma unroll
    for (int j = 0; j < 4; ++j) {
        const float mean = stats[c + j] * invN;
        const float var  = stats[512 + c + j] * invN - mean * mean;
        o[j] = (hv[j] - mean) * rsqrtf(var + 1e-5f) * gamma[c + j] + beta[c + j];
    }
    float4 out = {o[0], o[1], o[2], o[3]};
    *(float4*)&hbuf[i4] = out;
}

extern "C" void kernel_launch(void* const* d_in, const int* in_sizes, int n_in,
                              void* d_out, int out_size, void* d_ws, size_t ws_size,
                              hipStream_t stream)
{
    const float* x     = (const float*)d_in[0];
    const int*   ei    = (const int*)d_in[1];
    // d_in[2] virt_h, d_in[3] virt_edge_index unused (use_virt_nodes=False)
    const float* Wq    = (const float*)d_in[4];
    const float* Wk    = (const float*)d_in[5];
    const float* Wv    = (const float*)d_in[6];
    const float* gamma = (const float*)d_in[7];
    const float* beta  = (const float*)d_in[8];
    float* out = (float*)d_out;

    char* ws = (char*)d_ws;
    unsigned short* qkv    = (unsigned short*)ws;                  // 123,076,608 (M_PAD rows)
    unsigned short* xb     = (unsigned short*)(ws + 123076608);    //  41,025,536 (M_PAD rows)
    unsigned short* Wt     = (unsigned short*)(ws + 164102144);    //   1,572,864
    int*            counts = (int*)           (ws + 165675008);    //     160,000
    int*            cursor = (int*)           (ws + 165835008);    //     160,000
    int*            row_ptr= (int*)           (ws + 165995008);    //     160,016
    unsigned short* col    = (unsigned short*)(ws + 166155024);    //   1,280,032
    float*          stats  = (float*)         (ws + 167435056);    //       4,096
    float*          ksc    = (float*)         (ws + 167439152);    //   1,282,048 (M_PAD*8*4)
    float*          vsc    = (float*)         (ws + 168721200);    //   1,282,048
    // total ws use: 170,003,248 B
    // NOTE: ksc/vsc CANNOT alias xb — GEMM reads A-panels concurrently with
    // its epilogue writing the scales.

    hipMemsetAsync(counts, 0, 160000, stream);
    hipMemsetAsync(cursor, 0, 160000, stream);
    hipMemsetAsync(stats,  0, 4096,   stream);
    hipMemsetAsync(xb + (size_t)N_NODES * 512, 0, (size_t)(M_PAD - N_NODES) * 512 * 2, stream);

    cast_x<<<10000, 256, 0, stream>>>(x, xb);
    cast_wt<<<dim3(16, 16, 3), 256, 0, stream>>>(Wq, Wk, Wv, Wt);
    csr_hist<<<2500, 256, 0, stream>>>(ei, counts);
    csr_scan<<<1, 1024, 0, stream>>>(counts, row_ptr);
    csr_scatter<<<2500, 256, 0, stream>>>(ei, row_ptr, cursor, col);
    qkv_gemm_mfma<<<3756, 256, 0, stream>>>(xb, Wt, qkv, ksc, vsc);
    edge_fused<<<20000, 128, 0, stream>>>(qkv, ksc, vsc, row_ptr, col, x, out);
    stats_pass<<<500, 512, 0, stream>>>(out, stats);
    bn_norm<<<20000, 256, 0, stream>>>(out, stats, gamma, beta);
}

// Round 24
// 429.459 us; speedup vs baseline: 1.0233x; 1.0233x over previous
//
#include <hip/hip_runtime.h>
#include <hip/hip_bf16.h>

#define N_NODES 40000
#define M_PAD   40064            // 313 * 128
#define N_EDGES 640000
#define DIM_H 512
#define QKV_STRIDE 1536          // row stride in u16 units (3072 B)
#define ROW_BYTES 3072
// Row layout (bytes): [0,1024) Q bf16 | [1024,1536) K int8 | [1536,1568) kscale[8] f32
//                     [1568,1600) vscale[8] f32 | [2048,2560) V int8 | rest dead
// r24: REVERT to r19 (best measured: 431.2us). r20/r23's side-array scales
// were WORSE (134us, FETCH 431MB, occ 73% -> gather thrash). Inline scales
// ride the row's open DRAM pages; 40% occ at 56 VGPR is the sweet spot.

typedef __attribute__((ext_vector_type(8))) short bf16x8_t;  // 8 bf16 = 4 VGPR
typedef __attribute__((ext_vector_type(4))) float f32x4_t;   // MFMA acc
typedef __attribute__((ext_vector_type(8))) unsigned short u16x8_t;

static __device__ __forceinline__ unsigned short f2bf(float f) {
    __hip_bfloat16 h = __float2bfloat16(f);
    return *reinterpret_cast<unsigned short*>(&h);
}
static __device__ __forceinline__ float bf2f(unsigned short u) {
    return __uint_as_float(((unsigned)u) << 16);
}
// async global->LDS, 16B per lane (linear LDS dest = uniform base + lane*16).
static __device__ __forceinline__ void gll16(const void* g, void* l) {
    __builtin_amdgcn_global_load_lds(
        (const __attribute__((address_space(1))) unsigned int*)g,
        (__attribute__((address_space(3))) unsigned int*)l, 16, 0, 0);
}

// ---------------------------------------------------------------------------
// K0a: cast x (f32) -> xb (bf16). 8 elems/thread. 10000 blocks exact.
// ---------------------------------------------------------------------------
__global__ __launch_bounds__(256)
void cast_x(const float* __restrict__ x, unsigned short* __restrict__ xb)
{
    const size_t i = ((size_t)blockIdx.x * 256 + threadIdx.x) * 8;
    const float4 v0 = *(const float4*)&x[i];
    const float4 v1 = *(const float4*)&x[i + 4];
    u16x8_t o;
    o[0] = f2bf(v0.x); o[1] = f2bf(v0.y); o[2] = f2bf(v0.z); o[3] = f2bf(v0.w);
    o[4] = f2bf(v1.x); o[5] = f2bf(v1.y); o[6] = f2bf(v1.z); o[7] = f2bf(v1.w);
    *(u16x8_t*)&xb[i] = o;
}

// ---------------------------------------------------------------------------
// K0b: cast+transpose W[k][n] -> Wt[m][n][k] (bf16). grid (16,16,3).
// ---------------------------------------------------------------------------
__global__ __launch_bounds__(256)
void cast_wt(const float* __restrict__ Wq,
             const float* __restrict__ Wk,
             const float* __restrict__ Wv,
             unsigned short* __restrict__ Wt)
{
    __shared__ float tile[32][33];
    const float* W = (blockIdx.z == 0) ? Wq : (blockIdx.z == 1) ? Wk : Wv;
    unsigned short* Wo = Wt + (size_t)blockIdx.z * 512 * 512;
    const int k0 = blockIdx.x * 32, n0 = blockIdx.y * 32;
    const int tx = threadIdx.x & 31, ty0 = threadIdx.x >> 5;
    #pragma unroll
    for (int p = 0; p < 4; ++p) {
        const int r = ty0 + p * 8;
        tile[r][tx] = W[(size_t)(k0 + r) * 512 + n0 + tx];
    }
    __syncthreads();
    #pragma unroll
    for (int p = 0; p < 4; ++p) {
        const int r = ty0 + p * 8;
        Wo[(size_t)(n0 + r) * 512 + k0 + tx] = f2bf(tile[tx][r]);
    }
}

// ---------------------------------------------------------------------------
// K1: QKV GEMM (r13 core: 128x128 tile, BK=32, chunk-swizzled staging,
// XCD-bijective remap). FUSED EPILOGUE QUANT (r19): Q blocks write bf16;
// K/V blocks quantize f32 acc -> int8 with per-(row,head) scale (wave
// quadrant == one head; absmax reduce = 3 fmaxf + 4 shfl_xor). Scales
// stored inline at row bytes 1536+hd*4 (K) / 1568+hd*4 (V).
// ---------------------------------------------------------------------------
__global__ __launch_bounds__(256)
void qkv_gemm_mfma(const unsigned short* __restrict__ xb,
                   const unsigned short* __restrict__ Wt,
                   unsigned short* __restrict__ qkv)
{
    __shared__ short Asub[128 * 32];
    __shared__ short Bsub[128 * 32];

    const int orig = blockIdx.x;             // 0..3755
    const int q = 469, rmod = 4;             // 3756 = 8*469 + 4
    const int xcd = orig & 7;
    const int sub = orig >> 3;
    const int wg = (xcd < rmod ? xcd * (q + 1) : rmod * (q + 1) + (xcd - rmod) * q) + sub;
    const int n0g = (wg % 12) * 128;
    const int m0  = (wg / 12) * 128;

    const int wsel = n0g >> 9;
    const int nc0  = n0g & 511;
    const int tid = threadIdx.x;
    const int l = tid & 63;
    const int w = tid >> 6;
    const int wr = w >> 1, wc = w & 1;
    const int lr = l & 15;
    const int lk = (l >> 4) * 8;             // chunk index = lk>>3 in {0..3}

    const int idx0 = tid, idx1 = 256 + tid;
    const int ar0 = idx0 >> 2, ac0 = (((idx0 & 3) ^ ((idx0 >> 3) & 3))) * 8;
    const int ar1 = idx1 >> 2, ac1 = (((idx1 & 3) ^ ((idx1 >> 3) & 3))) * 8;

    const unsigned short* Abase = xb + (size_t)m0 * 512;
    const unsigned short* Bbase = Wt + (size_t)wsel * 262144 + (size_t)nc0 * 512;

    f32x4_t acc[4][4];
    #pragma unroll
    for (int i = 0; i < 4; ++i)
        #pragma unroll
        for (int j = 0; j < 4; ++j)
            acc[i][j] = {0.f, 0.f, 0.f, 0.f};

    for (int k0 = 0; k0 < 512; k0 += 32) {
        gll16(Abase + (size_t)ar0 * 512 + k0 + ac0, &Asub[idx0 * 8]);
        gll16(Abase + (size_t)ar1 * 512 + k0 + ac1, &Asub[idx1 * 8]);
        gll16(Bbase + (size_t)ar0 * 512 + k0 + ac0, &Bsub[idx0 * 8]);
        gll16(Bbase + (size_t)ar1 * 512 + k0 + ac1, &Bsub[idx1 * 8]);
        __syncthreads();
        bf16x8_t a[4], b[4];
        #pragma unroll
        for (int fm = 0; fm < 4; ++fm) {
            const int Ra = wr * 64 + fm * 16 + lr;
            const int pa = (((lk >> 3) ^ ((Ra >> 1) & 3))) << 3;
            a[fm] = *(const bf16x8_t*)&Asub[Ra * 32 + pa];
        }
        #pragma unroll
        for (int fn = 0; fn < 4; ++fn) {
            const int Rb = wc * 64 + fn * 16 + lr;
            const int pb = (((lk >> 3) ^ ((Rb >> 1) & 3))) << 3;
            b[fn] = *(const bf16x8_t*)&Bsub[Rb * 32 + pb];
        }
        #pragma unroll
        for (int fm = 0; fm < 4; ++fm)
            #pragma unroll
            for (int fn = 0; fn < 4; ++fn)
                acc[fm][fn] = __builtin_amdgcn_mfma_f32_16x16x32_bf16(
                                  a[fm], b[fn], acc[fm][fn], 0, 0, 0);
        __syncthreads();
    }

    if (wsel == 0) {
        // Q section: bf16 write (unchanged)
        #pragma unroll
        for (int fm = 0; fm < 4; ++fm)
            #pragma unroll
            for (int fn = 0; fn < 4; ++fn)
                #pragma unroll
                for (int j = 0; j < 4; ++j) {
                    const int row = m0 + wr * 64 + fm * 16 + (l >> 4) * 4 + j;
                    const int col = n0g + wc * 64 + fn * 16 + lr;
                    qkv[(size_t)row * QKV_STRIDE + col] = f2bf(acc[fm][fn][j]);
                }
    } else {
        // K (wsel==1) / V (wsel==2): int8 + inline per-(row,head) scale.
        const int hd     = (nc0 >> 6) + wc;              // head 0..7
        const int sbase  = (wsel == 1) ? 1024 : 2048;    // int8 data base
        const int scbase = (wsel == 1) ? 1536 : 1568;    // scale base
        #pragma unroll
        for (int fm = 0; fm < 4; ++fm)
            #pragma unroll
            for (int j = 0; j < 4; ++j) {
                const int row = m0 + wr * 64 + fm * 16 + (l >> 4) * 4 + j;
                float m = 0.f;
                #pragma unroll
                for (int fn = 0; fn < 4; ++fn)
                    m = fmaxf(m, fabsf(acc[fm][fn][j]));
                m = fmaxf(m, __shfl_xor(m, 1, 64));
                m = fmaxf(m, __shfl_xor(m, 2, 64));
                m = fmaxf(m, __shfl_xor(m, 4, 64));
                m = fmaxf(m, __shfl_xor(m, 8, 64));
                const float inv = (m > 0.f) ? 127.0f / m : 0.f;
                char* rowb = (char*)qkv + (size_t)row * ROW_BYTES;
                #pragma unroll
                for (int fn = 0; fn < 4; ++fn) {
                    const int qv = (int)rintf(acc[fm][fn][j] * inv);
                    rowb[sbase + hd * 64 + fn * 16 + lr] = (char)(signed char)qv;
                }
                if (lr == 0)
                    *(float*)(rowb + scbase + hd * 4) = m * (1.0f / 127.0f);
            }
    }
}

// ---------------------------------------------------------------------------
// CSR build (by dst).
// ---------------------------------------------------------------------------
__global__ __launch_bounds__(256)
void csr_hist(const int* __restrict__ ei, int* __restrict__ counts)
{
    const int e = blockIdx.x * 256 + threadIdx.x;   // 2500 blocks exact
    atomicAdd(&counts[ei[N_EDGES + e]], 1);
}

__global__ __launch_bounds__(1024)
void csr_scan(const int* __restrict__ counts, int* __restrict__ row_ptr)
{
    __shared__ int part[1024];
    const int t = threadIdx.x;
    const int base = t * 40;
    int s = 0;
    for (int i = 0; i < 40; ++i) {
        const int idx = base + i;
        if (idx < N_NODES) s += counts[idx];
    }
    part[t] = s;
    __syncthreads();
    for (int off = 1; off < 1024; off <<= 1) {
        int v = (t >= off) ? part[t - off] : 0;
        __syncthreads();
        part[t] += v;
        __syncthreads();
    }
    int run = (t == 0) ? 0 : part[t - 1];
    for (int i = 0; i < 40; ++i) {
        const int idx = base + i;
        if (idx < N_NODES) { row_ptr[idx] = run; run += counts[idx]; }
    }
    if (t == 0) row_ptr[N_NODES] = part[1023];
}

__global__ __launch_bounds__(256)
void csr_scatter(const int* __restrict__ ei, const int* __restrict__ row_ptr,
                 int* __restrict__ cursor, unsigned short* __restrict__ col)
{
    const int e = blockIdx.x * 256 + threadIdx.x;   // 2500 blocks exact
    const int dst = ei[N_EDGES + e];
    const int pos = atomicAdd(&cursor[dst], 1);
    col[row_ptr[dst] + pos] = (unsigned short)ei[e];
}

// ---------------------------------------------------------------------------
// K2: FUSED edge pass (r16/r18 best config: 2-wave blocks, grid 20000).
// Per-head scales read INLINE from the row (bytes 1536+g*4 / 1568+g*4).
// ---------------------------------------------------------------------------
__global__ __launch_bounds__(128)
void edge_fused(const unsigned short* __restrict__ qkv,
                const int* __restrict__ row_ptr,
                const unsigned short* __restrict__ col,
                const float* __restrict__ x,
                float* __restrict__ out)
{
    const int node = blockIdx.x * 2 + (threadIdx.x >> 6);
    const int lane = threadIdx.x & 63;
    const int g = lane >> 3;
    const int d0b = lane * 8;

    const u16x8_t q8 = *(const u16x8_t*)(qkv + (size_t)node * QKV_STRIDE + lane * 8);
    float q[8];
    #pragma unroll
    for (int j = 0; j < 8; ++j) q[j] = bf2f(q8[j]);

    const char* qb = (const char*)qkv;
    float acc[8] = {0.f, 0.f, 0.f, 0.f, 0.f, 0.f, 0.f, 0.f};
    float zsum = 0.f;
    const int start = row_ptr[node];
    const int end   = row_ptr[node + 1];

    int e = start;
    for (; e + 4 <= end; e += 4) {
        const int s0 = col[e], s1 = col[e + 1], s2 = col[e + 2], s3 = col[e + 3];
        const char* rb0 = qb + (size_t)s0 * ROW_BYTES;
        const char* rb1 = qb + (size_t)s1 * ROW_BYTES;
        const char* rb2 = qb + (size_t)s2 * ROW_BYTES;
        const char* rb3 = qb + (size_t)s3 * ROW_BYTES;
        const uint2 k0 = *(const uint2*)(rb0 + 1024 + d0b);
        const uint2 k1 = *(const uint2*)(rb1 + 1024 + d0b);
        const uint2 k2 = *(const uint2*)(rb2 + 1024 + d0b);
        const uint2 k3 = *(const uint2*)(rb3 + 1024 + d0b);
        const uint2 v0 = *(const uint2*)(rb0 + 2048 + d0b);
        const uint2 v1 = *(const uint2*)(rb1 + 2048 + d0b);
        const uint2 v2 = *(const uint2*)(rb2 + 2048 + d0b);
        const uint2 v3 = *(const uint2*)(rb3 + 2048 + d0b);
        const float ks0 = *(const float*)(rb0 + 1536 + g * 4);
        const float ks1 = *(const float*)(rb1 + 1536 + g * 4);
        const float ks2 = *(const float*)(rb2 + 1536 + g * 4);
        const float ks3 = *(const float*)(rb3 + 1536 + g * 4);
        const signed char* ck0 = (const signed char*)&k0;
        const signed char* ck1 = (const signed char*)&k1;
        const signed char* ck2 = (const signed char*)&k2;
        const signed char* ck3 = (const signed char*)&k3;
        float p0 = 0.f, p1 = 0.f, p2 = 0.f, p3 = 0.f;
        #pragma unroll
        for (int j = 0; j < 8; ++j) {
            p0 = fmaf((float)ck0[j], q[j], p0);
            p1 = fmaf((float)ck1[j], q[j], p1);
            p2 = fmaf((float)ck2[j], q[j], p2);
            p3 = fmaf((float)ck3[j], q[j], p3);
        }
        p0 += __shfl_xor(p0, 1, 64); p0 += __shfl_xor(p0, 2, 64); p0 += __shfl_xor(p0, 4, 64);
        p1 += __shfl_xor(p1, 1, 64); p1 += __shfl_xor(p1, 2, 64); p1 += __shfl_xor(p1, 4, 64);
        p2 += __shfl_xor(p2, 1, 64); p2 += __shfl_xor(p2, 2, 64); p2 += __shfl_xor(p2, 4, 64);
        p3 += __shfl_xor(p3, 1, 64); p3 += __shfl_xor(p3, 2, 64); p3 += __shfl_xor(p3, 4, 64);
        const float sc0 = __expf(fminf(fmaxf(p0 * ks0 * 0.125f, -5.f), 5.f));
        const float sc1 = __expf(fminf(fmaxf(p1 * ks1 * 0.125f, -5.f), 5.f));
        const float sc2 = __expf(fminf(fmaxf(p2 * ks2 * 0.125f, -5.f), 5.f));
        const float sc3 = __expf(fminf(fmaxf(p3 * ks3 * 0.125f, -5.f), 5.f));
        zsum += (sc0 + sc1) + (sc2 + sc3);
        const float scv0 = sc0 * *(const float*)(rb0 + 1568 + g * 4);
        const float scv1 = sc1 * *(const float*)(rb1 + 1568 + g * 4);
        const float scv2 = sc2 * *(const float*)(rb2 + 1568 + g * 4);
        const float scv3 = sc3 * *(const float*)(rb3 + 1568 + g * 4);
        const signed char* cv0 = (const signed char*)&v0;
        const signed char* cv1 = (const signed char*)&v1;
        const signed char* cv2 = (const signed char*)&v2;
        const signed char* cv3 = (const signed char*)&v3;
        #pragma unroll
        for (int j = 0; j < 8; ++j) {
            float a = acc[j];
            a = fmaf(scv0, (float)cv0[j], a);
            a = fmaf(scv1, (float)cv1[j], a);
            a = fmaf(scv2, (float)cv2[j], a);
            a = fmaf(scv3, (float)cv3[j], a);
            acc[j] = a;
        }
    }
    for (; e < end; ++e) {
        const int s0 = col[e];
        const char* rb0 = qb + (size_t)s0 * ROW_BYTES;
        const uint2 k0 = *(const uint2*)(rb0 + 1024 + d0b);
        const uint2 v0 = *(const uint2*)(rb0 + 2048 + d0b);
        const float ks0 = *(const float*)(rb0 + 1536 + g * 4);
        const signed char* ck0 = (const signed char*)&k0;
        float p0 = 0.f;
        #pragma unroll
        for (int j = 0; j < 8; ++j) p0 = fmaf((float)ck0[j], q[j], p0);
        p0 += __shfl_xor(p0, 1, 64); p0 += __shfl_xor(p0, 2, 64); p0 += __shfl_xor(p0, 4, 64);
        const float sc0 = __expf(fminf(fmaxf(p0 * ks0 * 0.125f, -5.f), 5.f));
        zsum += sc0;
        const float scv0 = sc0 * *(const float*)(rb0 + 1568 + g * 4);
        const signed char* cv0 = (const signed char*)&v0;
        #pragma unroll
        for (int j = 0; j < 8; ++j) acc[j] = fmaf(scv0, (float)cv0[j], acc[j]);
    }

    const float invz = 1.0f / (zsum + 1e-6f);
    const float* xr = x + (size_t)node * 512 + lane * 8;
    float xv[8];
    #pragma unroll
    for (int j = 0; j < 8; ++j) xv[j] = __builtin_nontemporal_load(xr + j);
    float* orow = out + (size_t)node * 512 + lane * 8;
    #pragma unroll
    for (int j = 0; j < 8; ++j)
        __builtin_nontemporal_store(xv[j] + acc[j] * invz, orow + j);
}

// ---------------------------------------------------------------------------
// K3: BN column stats over final h (in d_out). thread=col, 80 rows/block.
// ---------------------------------------------------------------------------
__global__ __launch_bounds__(512)
void stats_pass(const float* __restrict__ hbuf, float* __restrict__ stats)
{
    const int c  = threadIdx.x;
    const int r0 = blockIdx.x * 80;
    float sum = 0.f, sq = 0.f;
    for (int i = 0; i < 80; ++i) {
        const float hv = hbuf[(size_t)(r0 + i) * 512 + c];
        sum += hv; sq += hv * hv;
    }
    atomicAdd(&stats[c], sum);
    atomicAdd(&stats[512 + c], sq);
}

// ---------------------------------------------------------------------------
// K4: BatchNorm normalize in place. float4/thread, 20000 blocks exact.
// ---------------------------------------------------------------------------
__global__ __launch_bounds__(256)
void bn_norm(float* __restrict__ hbuf,
             const float* __restrict__ stats,
             const float* __restrict__ gamma,
             const float* __restrict__ beta)
{
    const size_t i4 = ((size_t)blockIdx.x * 256 + threadIdx.x) * 4;
    const int c = (int)(i4 & 511);
    const float invN = 1.0f / 40000.0f;
    float4 h = *(float4*)&hbuf[i4];
    float hv[4] = {h.x, h.y, h.z, h.w};
    float o[4];
    #pragma unroll
    for (int j = 0; j < 4; ++j) {
        const float mean = stats[c + j] * invN;
        const float var  = stats[512 + c + j] * invN - mean * mean;
        o[j] = (hv[j] - mean) * rsqrtf(var + 1e-5f) * gamma[c + j] + beta[c + j];
    }
    float4 out = {o[0], o[1], o[2], o[3]};
    *(float4*)&hbuf[i4] = out;
}

extern "C" void kernel_launch(void* const* d_in, const int* in_sizes, int n_in,
                              void* d_out, int out_size, void* d_ws, size_t ws_size,
                              hipStream_t stream)
{
    const float* x     = (const float*)d_in[0];
    const int*   ei    = (const int*)d_in[1];
    // d_in[2] virt_h, d_in[3] virt_edge_index unused (use_virt_nodes=False)
    const float* Wq    = (const float*)d_in[4];
    const float* Wk    = (const float*)d_in[5];
    const float* Wv    = (const float*)d_in[6];
    const float* gamma = (const float*)d_in[7];
    const float* beta  = (const float*)d_in[8];
    float* out = (float*)d_out;

    char* ws = (char*)d_ws;
    unsigned short* qkv    = (unsigned short*)ws;                  // 123,076,608 (M_PAD rows)
    unsigned short* xb     = (unsigned short*)(ws + 123076608);    //  41,025,536 (M_PAD rows)
    unsigned short* Wt     = (unsigned short*)(ws + 164102144);    //   1,572,864
    int*            counts = (int*)           (ws + 165675008);    //     160,000
    int*            cursor = (int*)           (ws + 165835008);    //     160,000
    int*            row_ptr= (int*)           (ws + 165995008);    //     160,016
    unsigned short* col    = (unsigned short*)(ws + 166155024);    //   1,280,032
    float*          stats  = (float*)         (ws + 167435056);    //       4,096
    // total ws use: 167,439,152 B

    hipMemsetAsync(counts, 0, 160000, stream);
    hipMemsetAsync(cursor, 0, 160000, stream);
    hipMemsetAsync(stats,  0, 4096,   stream);
    hipMemsetAsync(xb + (size_t)N_NODES * 512, 0, (size_t)(M_PAD - N_NODES) * 512 * 2, stream);

    cast_x<<<10000, 256, 0, stream>>>(x, xb);
    cast_wt<<<dim3(16, 16, 3), 256, 0, stream>>>(Wq, Wk, Wv, Wt);
    csr_hist<<<2500, 256, 0, stream>>>(ei, counts);
    csr_scan<<<1, 1024, 0, stream>>>(counts, row_ptr);
    csr_scatter<<<2500, 256, 0, stream>>>(ei, row_ptr, cursor, col);
    qkv_gemm_mfma<<<3756, 256, 0, stream>>>(xb, Wt, qkv);
    edge_fused<<<20000, 128, 0, stream>>>(qkv, row_ptr, col, x, out);
    stats_pass<<<500, 512, 0, stream>>>(out, stats);
    bn_norm<<<20000, 256, 0, stream>>>(out, stats, gamma, beta);
}